// Round 5
// baseline (1283.915 us; speedup 1.0000x reference)
//
#include <hip/hip_runtime.h>

// Residual VQ forward, MFMA candidates + R3-replica exact selection. R13:
//  - k_gemm_topk back to 128x128 / 4-wave geometry with TWO-buffer LDS
//    (34304 B -> 4 resident blocks/CU = 16 waves: hide per-block overhead H
//    across blocks; R12's 256x2/1-resident showed K-loop tweaks are ~null and
//    per-block epilogue/prologue overhead dominates at K=512).
//  - epilogue scan: 4 independent 8-insert chains (contiguous col ranges) +
//    merge, replacing one serial 32-insert chain (1.6x less serial depth, 4x
//    ILP). Tie-order among equal-sb entries is provably irrelevant (both land
//    in selupd's rescore window; exact rescore has exact tie-break).
// R11: fused init, b128 epilogue reads, setprio. R10: selupd coalesced
// staging. R9: XCD-pinned swizzle (FETCH ideal), proven drain K-loop.
// d_out flat: [quantized (B,T,D) | indices (B,T,Q) as float | loss scalar]
// Selection arithmetic (validated R3/R5/R6/R7, bit-exact vs reference):
//   sb = c2 - 2*dot_bf16 candidates (top-4 per 128-code block);
//   exact rescore = ascending 512-step fmaf chain, s = fl(fl(r2-2d)+c2),
//   contract off, lowest-index tie-break; r2/c2 numpy-pairwise order.

constexpr int DIM   = 512;
constexpr int KCB   = 2048;
constexpr int NQ    = 8;
constexpr int NTOK  = 8 * 2048;       // 16384
constexpr int QELEM = NTOK * DIM;     // 8388608
constexpr int NBLK  = KCB / 128;      // 16 column blocks
constexpr float WINDOW = 1e-3f;       // worst-case bf16 score err ~4.5e-4

using short8  = __attribute__((ext_vector_type(8))) short;
using float4v = __attribute__((ext_vector_type(4))) float;

__device__ __forceinline__ unsigned short f2bf(float f) {
    unsigned u = __float_as_uint(f);
    return (unsigned short)((u + 0x7FFFu + ((u >> 16) & 1u)) >> 16);   // RNE
}

__device__ __forceinline__ void gl2lds16(const void* g, void* l) {
    __builtin_amdgcn_global_load_lds(
        (__attribute__((address_space(1))) void*)g,
        (__attribute__((address_space(3))) void*)l, 16, 0, 0);
}

struct Top4 { float s[4]; int i[4]; };
__device__ __forceinline__ void t4_init(Top4& t) {
#pragma unroll
    for (int j = 0; j < 4; ++j) { t.s[j] = 3.0e38f; t.i[j] = 0x7FFFFFFF; }
}
__device__ __forceinline__ void t4_ins(Top4& t, float s, int idx) {
    if (s < t.s[3]) {
        if (s < t.s[2]) { t.s[3] = t.s[2]; t.i[3] = t.i[2];
            if (s < t.s[1]) { t.s[2] = t.s[1]; t.i[2] = t.i[1];
                if (s < t.s[0]) { t.s[1] = t.s[0]; t.i[1] = t.i[0]; t.s[0] = s; t.i[0] = idx; }
                else            { t.s[1] = s; t.i[1] = idx; }
            } else { t.s[2] = s; t.i[2] = idx; }
        } else { t.s[3] = s; t.i[3] = idx; }
    }
}

// Fused init: blocks [0,4096) handle x rows (copy R, cast Rb, np-pairwise r2);
// blocks [4096,8192) handle codebook rows (cast Cbb, np-pairwise c2).
__global__ __launch_bounds__(256) void k_initnorm(
        const float* __restrict__ x, const float* __restrict__ cbs,
        float4* __restrict__ R, ushort4* __restrict__ Rb, ushort4* __restrict__ Cbb,
        float* __restrict__ r2, float* __restrict__ c2)
{
#pragma clang fp contract(off)
    __shared__ float buf[4][DIM];
    __shared__ float accs[4][32];
    const int w = threadIdx.x >> 6, lane = threadIdx.x & 63;
    const bool isX = blockIdx.x < (NTOK / 4);
    const int row = (isX ? blockIdx.x : blockIdx.x - NTOK / 4) * 4 + w;

    const float* src = isX ? x : cbs;
    const float4* a4 = reinterpret_cast<const float4*>(src + (size_t)row * DIM);
    float4 v0 = a4[lane], v1 = a4[lane + 64];

    ushort4 b0 = make_ushort4(f2bf(v0.x), f2bf(v0.y), f2bf(v0.z), f2bf(v0.w));
    ushort4 b1 = make_ushort4(f2bf(v1.x), f2bf(v1.y), f2bf(v1.z), f2bf(v1.w));
    if (isX) {
        R [(size_t)row * 128 + lane]      = v0;
        R [(size_t)row * 128 + lane + 64] = v1;
        Rb[(size_t)row * 128 + lane]      = b0;
        Rb[(size_t)row * 128 + lane + 64] = b1;
    } else {
        Cbb[(size_t)row * 128 + lane]      = b0;
        Cbb[(size_t)row * 128 + lane + 64] = b1;
    }

    float4* b4 = reinterpret_cast<float4*>(buf[w]);
    b4[lane]      = v0;
    b4[lane + 64] = v1;
    __syncthreads();
    if (lane < 32) {
        int blk = lane >> 3, j = lane & 7;
        const float* p = buf[w] + blk * 128 + j;
        float x0 = p[0];
        float acc = x0 * x0;
#pragma unroll
        for (int m = 1; m < 16; ++m) { float xx = p[8 * m]; acc = acc + xx * xx; }
        accs[w][lane] = acc;
    }
    __syncthreads();
    if (lane == 0) {
        float B[4];
#pragma unroll
        for (int blk = 0; blk < 4; ++blk) {
            const float* r = &accs[w][blk * 8];
            B[blk] = ((r[0] + r[1]) + (r[2] + r[3])) + ((r[4] + r[5]) + (r[6] + r[7]));
        }
        float out = (B[0] + B[1]) + (B[2] + B[3]);
        if (isX) r2[row] = out; else c2[row] = out;
    }
}

// 128x128 tile bf16 MFMA GEMM (A.B^T) + per-row top-4 over the 128 cols.
// Two-buffer staging (34304B LDS -> 4 resident blocks), proven drain loop.
__global__ __launch_bounds__(256, 4) void k_gemm_topk(
        const unsigned short* __restrict__ Rb, const unsigned short* __restrict__ Cbb,
        const float* __restrict__ c2, float* __restrict__ candS, int* __restrict__ candI)
{
    // [0,16384): A0|A1 (8KB each).  [16384,32768): B0|B1.
    // Epilogue: scb fp32 [64][132] at 0 (33792B, aliases staging).
    // c2s fp32[128] at 33792 (never aliased). Total 34304 -> 4 blocks/CU.
    __shared__ __align__(16) char smem[34304];
    unsigned short* A0 = (unsigned short*)smem;                   // 4096 shorts/buf
    unsigned short* B0 = (unsigned short*)(smem + 16384);
    float*  scb = (float*)smem;
    float*  c2s = (float*)(smem + 33792);

    const int tid  = threadIdx.x;
    const int wid  = tid >> 6, lane = tid & 63;
    const int quad = lane >> 4, l16 = lane & 15;

    // dispatch-linear id (x fastest); HW round-robins XCD by L%8.
    // mb = (L&7)*16 + (L>>3)/16 -> each XCD owns 16 consecutive mb panels,
    // nb = (L>>3)&15            -> nb iterates fastest within an XCD.
    const int L    = blockIdx.y * NBLK + blockIdx.x;
    const int slot = L >> 3;
    const int mb   = (L & 7) * 16 + (slot >> 4);
    const int nb   = slot & 15;

    const int tok0 = mb * 128, n0 = nb * 128;
    const int nw = (wid & 1) * 64;
    const int fbA = (wid >> 1) * 4;      // base mi for this wave's A rows
    const int fbB = (wid & 1) * 4;       // base nj for this wave's B rows

    if (tid < 128) c2s[tid] = c2[n0 + tid];

    float4v acc[4][4];
    float4v zero = {0.f, 0.f, 0.f, 0.f};
#pragma unroll
    for (int mi = 0; mi < 4; ++mi)
#pragma unroll
        for (int nj = 0; nj < 4; ++nj) acc[mi][nj] = zero;

    // stage tile kb into buffer b: lane (quad,l16) of wave wid loads
    // row (i*4+wid)*16+l16, k-chunk quad -> LDS unit i*256+wid*64+lane.
    auto stage = [&](int b, int kb) {
        unsigned short* Ad = A0 + b * 4096;
        unsigned short* Bd = B0 + b * 4096;
#pragma unroll
        for (int i = 0; i < 2; ++i) {
            int mi_abs = i * 4 + wid;
            gl2lds16(&Rb[(size_t)(tok0 + mi_abs * 16 + l16) * DIM + kb + quad * 8],
                     Ad + (size_t)(i * 256 + wid * 64) * 8);
            gl2lds16(&Cbb[(size_t)(n0 + mi_abs * 16 + l16) * DIM + kb + quad * 8],
                     Bd + (size_t)(i * 256 + wid * 64) * 8);
        }
    };

    auto compute = [&](int b) {
        const unsigned short* Ac = A0 + b * 4096;
        const unsigned short* Bc = B0 + b * 4096;
        short8 af[4], bf[4];
#pragma unroll
        for (int mi = 0; mi < 4; ++mi)
            af[mi] = *(const short8*)(Ac + ((size_t)(fbA + mi) * 64 + lane) * 8);
#pragma unroll
        for (int nj = 0; nj < 4; ++nj)
            bf[nj] = *(const short8*)(Bc + ((size_t)(fbB + nj) * 64 + lane) * 8);
        __builtin_amdgcn_s_setprio(1);                 // T5
#pragma unroll
        for (int mi = 0; mi < 4; ++mi)
#pragma unroll
            for (int nj = 0; nj < 4; ++nj)
                acc[mi][nj] = __builtin_amdgcn_mfma_f32_16x16x32_bf16(
                    af[mi], bf[nj], acc[mi][nj], 0, 0, 0);
        __builtin_amdgcn_s_setprio(0);
    };

    // K-loop: proven R9 drain pattern (syncthreads drains each wave's own
    // vmcnt before barrier -> buf[it&1] staged at it-1 is ready; stage of
    // buf[(it+1)&1] is safe because all waves finished reading it at it-1).
    stage(0, 0);
    for (int it = 0; it < 16; ++it) {
        __syncthreads();
        if (it < 15) stage((it + 1) & 1, (it + 1) * 32);
        compute(it & 1);
    }

    // epilogue: two 64-row halves; per-row top-4 of sb = c2 - 2*dot.
    // scb stride 132 (writes 2 lanes/bank, free). Reads: each part owns 32
    // contiguous cols -> 8x ds_read_b128. R13: 4 independent 8-insert chains
    // (cols 8c..8c+7, ascending) + ordered merge -> same candidate set,
    // 4x ILP / ~1.6x less serial depth than one 32-chain.
    const int row_ = tid >> 2, part_ = tid & 3;
    float4 c2r[8];
#pragma unroll
    for (int j = 0; j < 8; ++j)
        c2r[j] = *(const float4*)(c2s + part_ * 32 + 4 * j);

    for (int h = 0; h < 2; ++h) {
        __syncthreads();
        if ((wid >> 1) == h) {
#pragma unroll
            for (int mi = 0; mi < 4; ++mi)
#pragma unroll
                for (int nj = 0; nj < 4; ++nj) {
                    int r0 = mi * 16 + quad * 4;
                    int cc = nw + nj * 16 + l16;
#pragma unroll
                    for (int e = 0; e < 4; ++e)
                        scb[(r0 + e) * 132 + cc] = acc[mi][nj][e];
                }
        }
        __syncthreads();
        Top4 tc[4];
#pragma unroll
        for (int c = 0; c < 4; ++c) t4_init(tc[c]);
#pragma unroll
        for (int c = 0; c < 4; ++c) {
#pragma unroll
            for (int v = 0; v < 2; ++v) {
                int j = c * 2 + v;                     // float4 index, cols 8c+4v..
                float4 sv = *(const float4*)(scb + row_ * 132 + part_ * 32 + 4 * j);
                float4 cv = c2r[j];
                int c0 = n0 + part_ * 32 + 4 * j;
                t4_ins(tc[c], cv.x - 2.0f * sv.x, c0 + 0);
                t4_ins(tc[c], cv.y - 2.0f * sv.y, c0 + 1);
                t4_ins(tc[c], cv.z - 2.0f * sv.z, c0 + 2);
                t4_ins(tc[c], cv.w - 2.0f * sv.w, c0 + 3);
            }
        }
        // ordered merge of chains 1..3 into chain 0 (ascending col ranges;
        // strict < keeps lower-col side on ties -- and tie order is
        // output-irrelevant anyway, see header note).
#pragma unroll
        for (int c = 1; c < 4; ++c)
#pragma unroll
            for (int j = 0; j < 4; ++j) t4_ins(tc[0], tc[c].s[j], tc[c].i[j]);
        Top4 t = tc[0];
        // merge the 4 parts of this row (4 adjacent lanes of one wave)
#pragma unroll
        for (int k = 1; k <= 2; k <<= 1) {
            float os[4]; int oi[4];
#pragma unroll
            for (int j = 0; j < 4; ++j) {
                os[j] = __shfl_xor(t.s[j], k, 64);
                oi[j] = __shfl_xor(t.i[j], k, 64);
            }
#pragma unroll
            for (int j = 0; j < 4; ++j) t4_ins(t, os[j], oi[j]);
        }
        if (part_ == 0) {
            int token = tok0 + h * 64 + row_;
            size_t base = (size_t)token * 64 + (size_t)nb * 4;
#pragma unroll
            for (int j = 0; j < 4; ++j) { candS[base + j] = t.s[j]; candI[base + j] = t.i[j]; }
        }
    }
}

// Fused: select winner (R3-replica exact rescore of in-window candidates),
// update residual, recast bf16, np-ordered r2 for next level, loss partial.
__global__ __launch_bounds__(256) void k_selupd(
        const float* __restrict__ candS, const int* __restrict__ candI,
        float* __restrict__ R, const float* __restrict__ cbf,
        float* __restrict__ r2, const float* __restrict__ c2,
        float* __restrict__ idx_out, float* __restrict__ partial,
        ushort4* __restrict__ Rb, const float4* __restrict__ x, int level)
{
#pragma clang fp contract(off)
    __shared__ float buf[4][DIM];
    __shared__ float accs[4][32];
    __shared__ float shl[4];
    const int w = threadIdx.x >> 6, lane = threadIdx.x & 63;
    const int t = blockIdx.x * 4 + w;
    const bool last = (level == NQ - 1);

    // ---- stage R row (coalesced) into regs + per-wave LDS copy ----
    float4* r4 = reinterpret_cast<float4*>(R + (size_t)t * DIM);
    float4* b4 = reinterpret_cast<float4*>(buf[w]);
    float4 rr[2];
    rr[0] = r4[lane];      rr[1] = r4[lane + 64];
    b4[lane] = rr[0];      b4[lane + 64] = rr[1];

    // ---- select ----
    float sb = candS[(size_t)t * 64 + lane];
    int   ci = candI[(size_t)t * 64 + lane];
    float mn = sb;
#pragma unroll
    for (int off = 32; off; off >>= 1) mn = fminf(mn, __shfl_xor(mn, off, 64));
    unsigned long long mask = __ballot(sb <= mn + WINDOW);
    int ncand = __popcll(mask);
    int winner;
    if (ncand == 1) {
        winner = __shfl(ci, __ffsll(mask) - 1, 64);
    } else {
        int src = 0;
        if (lane < ncand) {
            unsigned long long mm = mask;
            for (int z = 0; z < lane; ++z) mm &= mm - 1;
            src = __ffsll(mm) - 1;
        }
        int cidx = __shfl(ci, src, 64);
        float s = 3.0e38f;
        int   si = 0x7FFFFFFF;
        if (lane < ncand) {
            const float4* cp4 = reinterpret_cast<const float4*>(cbf + (size_t)cidx * DIM);
            const float4* rp4 = reinterpret_cast<const float4*>(buf[w]);  // broadcast
            float d = 0.f;
#pragma unroll 4
            for (int j = 0; j < DIM / 4; ++j) {
                float4 cv = cp4[j];
                float4 rv = rp4[j];
                d = fmaf(rv.x, cv.x, d);
                d = fmaf(rv.y, cv.y, d);
                d = fmaf(rv.z, cv.z, d);
                d = fmaf(rv.w, cv.w, d);
            }
            float td = 2.0f * d;
            float a  = r2[t] - td;
            s  = a + c2[cidx];
            si = cidx;
        }
#pragma unroll
        for (int off = 32; off; off >>= 1) {
            float ov = __shfl_xor(s, off, 64);
            int   oi = __shfl_xor(si, off, 64);
            if (ov < s || (ov == s && oi < si)) { s = ov; si = oi; }
        }
        winner = si;
    }
    if (lane == 0) idx_out[(size_t)t * NQ + level] = (float)winner;

    // ---- update (reuses staged rr; values identical to re-reading R) ----
    const float4* c4 = reinterpret_cast<const float4*>(cbf + (size_t)winner * DIM);
    float ls = 0.f;
#pragma unroll
    for (int i = 0; i < 2; ++i) {
        int d = lane + 64 * i;
        float4 rv = rr[i], cv = c4[d];
        rv.x -= cv.x; rv.y -= cv.y; rv.z -= cv.z; rv.w -= cv.w;
        ls = ls + rv.x * rv.x; ls = ls + rv.y * rv.y;
        ls = ls + rv.z * rv.z; ls = ls + rv.w * rv.w;
        if (!last) {
            r4[d] = rv;
            b4[d] = rv;
            Rb[(size_t)t * 128 + d] = make_ushort4(f2bf(rv.x), f2bf(rv.y),
                                                   f2bf(rv.z), f2bf(rv.w));
        } else {
            float4 xv = x[(size_t)t * 128 + d];
            xv.x -= rv.x; xv.y -= rv.y; xv.z -= rv.z; xv.w -= rv.w;
            r4[d] = xv;                       // quantized = x - r_final (in d_out)
        }
    }

    if (!last) {
        __syncthreads();
        // np-pairwise r2 of the NEW residual (same order as k_initnorm)
        if (lane < 32) {
            int blk = lane >> 3, j = lane & 7;
            const float* p = buf[w] + blk * 128 + j;
            float x0 = p[0];
            float acc = x0 * x0;
#pragma unroll
            for (int m = 1; m < 16; ++m) { float xx = p[8 * m]; acc = acc + xx * xx; }
            accs[w][lane] = acc;
        }
        __syncthreads();
        if (lane == 0) {
            float B[4];
#pragma unroll
            for (int blk = 0; blk < 4; ++blk) {
                const float* r = &accs[w][blk * 8];
                B[blk] = ((r[0] + r[1]) + (r[2] + r[3])) + ((r[4] + r[5]) + (r[6] + r[7]));
            }
            r2[t] = (B[0] + B[1]) + (B[2] + B[3]);
        }
    }

    // ---- loss partial ----
#pragma unroll
    for (int off = 32; off; off >>= 1) ls += __shfl_down(ls, off, 64);
    if (lane == 0) shl[w] = ls;
    __syncthreads();
    if (threadIdx.x == 0) partial[blockIdx.x] = (shl[0] + shl[1]) + (shl[2] + shl[3]);
}

__global__ __launch_bounds__(256) void k_finalize_loss(const float* __restrict__ partial,
                                                       float* __restrict__ loss_out)
{
    double s = 0.0;
    for (int i = threadIdx.x; i < NQ * (NTOK / 4); i += 256) s += (double)partial[i];
#pragma unroll
    for (int off = 32; off; off >>= 1) s += __shfl_down(s, off, 64);
    __shared__ double sh[4];
    if ((threadIdx.x & 63) == 0) sh[threadIdx.x >> 6] = s;
    __syncthreads();
    if (threadIdx.x == 0) {
        double tot = (sh[0] + sh[1]) + (sh[2] + sh[3]);
        loss_out[0] = (float)(tot * 1.25 / ((double)NQ * (double)QELEM));
    }
}

extern "C" void kernel_launch(void* const* d_in, const int* in_sizes, int n_in,
                              void* d_out, int out_size, void* d_ws, size_t ws_size,
                              hipStream_t stream)
{
    const float* x   = (const float*)d_in[0];
    const float* cbs = (const float*)d_in[1];

    float* qout     = (float*)d_out;
    float* idx_out  = qout + QELEM;
    float* loss_out = idx_out + (size_t)NTOK * NQ;
    float* R        = qout;                 // residual lives in d_out (validated R5)

    char* ws = (char*)d_ws;
    size_t off = 0;
    unsigned short* Rb   = (unsigned short*)(ws + off); off += (size_t)QELEM * 2;  // 16MB
    unsigned short* Cbb  = (unsigned short*)(ws + off); off += (size_t)QELEM * 2;  // 16MB
    float*          c2   = (float*)(ws + off);          off += (size_t)NQ * KCB * 4;
    float*          r2   = (float*)(ws + off);          off += (size_t)NTOK * 4;
    float*          part = (float*)(ws + off);          off += (size_t)NQ * (NTOK / 4) * 4;
    float*          candS= (float*)(ws + off);          off += (size_t)NTOK * 64 * 4; // 4MB
    int*            candI= (int*)(ws + off);            off += (size_t)NTOK * 64 * 4; // 4MB

    // fused init: x rows (R copy, Rb cast, r2) + cb rows (Cbb cast, c2)
    k_initnorm<<<NTOK / 4 + NQ * KCB / 4, 256, 0, stream>>>(
        x, cbs, (float4*)R, (ushort4*)Rb, (ushort4*)Cbb, r2, c2);

    for (int q = 0; q < NQ; ++q) {
        const float*          cbq  = cbs + (size_t)q * KCB * DIM;
        const unsigned short* cbbq = Cbb + (size_t)q * KCB * DIM;
        const float*          c2q  = c2 + (size_t)q * KCB;
        dim3 g(NBLK, NTOK / 128);
        k_gemm_topk<<<g, 256, 0, stream>>>(Rb, cbbq, c2q, candS, candI);
        k_selupd<<<NTOK / 4, 256, 0, stream>>>(candS, candI, R, cbq, r2, c2q,
                                               idx_out, part + (size_t)q * (NTOK / 4),
                                               (ushort4*)Rb, (const float4*)x, q);
    }

    k_finalize_loss<<<1, 256, 0, stream>>>(part, loss_out);
}

// Round 6
// 1026.956 us; speedup vs baseline: 1.2502x; 1.2502x over previous
//
#include <hip/hip_runtime.h>

// Residual VQ forward, MFMA candidates + R3-replica exact selection. R14:
//  - k_gemm_topk: 256x256 tile, BK=64 (8 K-iters, HALF the barriers of R12),
//    2-buffer drain loop (R9-proven __syncthreads semantics). K accumulation
//    order still globally ascending (kk=0,1 per iter) -> scores BIT-IDENTICAL.
//  - c2s skewed layout offset(c)=c+4*(c>>5): kills the 4/8-way bank conflict
//    that was ALL of R11/R12's 786-917K conflict count (scb read/write are
//    provably uniform; c2s part*32 addresses all hit bank 4j).
//  - epilogue kept EXACTLY R12's (VGPR 124 proven no-spill; R13's tc[4]/
//    launch_bounds(256,4) combo spilled to scratch -> 128MB scratch writes).
// R12: 256^2 geometry. R11: fused init, b128 epilogue, setprio. R10: selupd
// coalesced staging. R9: XCD-pinned swizzle (FETCH ideal).
// d_out flat: [quantized (B,T,D) | indices (B,T,Q) as float | loss scalar]
// Selection arithmetic (validated R3/R5/R6/R7, bit-exact vs reference):
//   sb = c2 - 2*dot_bf16 candidates (top-4 per 128-code block);
//   exact rescore = ascending 512-step fmaf chain, s = fl(fl(r2-2d)+c2),
//   contract off, lowest-index tie-break; r2/c2 numpy-pairwise order.

constexpr int DIM   = 512;
constexpr int KCB   = 2048;
constexpr int NQ    = 8;
constexpr int NTOK  = 8 * 2048;       // 16384
constexpr int QELEM = NTOK * DIM;     // 8388608
constexpr int NBLK2 = KCB / 256;      // 8 column tiles (256 wide)
constexpr float WINDOW = 1e-3f;       // worst-case bf16 score err ~4.5e-4

using short8  = __attribute__((ext_vector_type(8))) short;
using float4v = __attribute__((ext_vector_type(4))) float;

__device__ __forceinline__ unsigned short f2bf(float f) {
    unsigned u = __float_as_uint(f);
    return (unsigned short)((u + 0x7FFFu + ((u >> 16) & 1u)) >> 16);   // RNE
}

__device__ __forceinline__ void gl2lds16(const void* g, void* l) {
    __builtin_amdgcn_global_load_lds(
        (__attribute__((address_space(1))) void*)g,
        (__attribute__((address_space(3))) void*)l, 16, 0, 0);
}

struct Top4 { float s[4]; int i[4]; };
__device__ __forceinline__ void t4_init(Top4& t) {
#pragma unroll
    for (int j = 0; j < 4; ++j) { t.s[j] = 3.0e38f; t.i[j] = 0x7FFFFFFF; }
}
__device__ __forceinline__ void t4_ins(Top4& t, float s, int idx) {
    if (s < t.s[3]) {
        if (s < t.s[2]) { t.s[3] = t.s[2]; t.i[3] = t.i[2];
            if (s < t.s[1]) { t.s[2] = t.s[1]; t.i[2] = t.i[1];
                if (s < t.s[0]) { t.s[1] = t.s[0]; t.i[1] = t.i[0]; t.s[0] = s; t.i[0] = idx; }
                else            { t.s[1] = s; t.i[1] = idx; }
            } else { t.s[2] = s; t.i[2] = idx; }
        } else { t.s[3] = s; t.i[3] = idx; }
    }
}

// Fused init: blocks [0,4096) handle x rows (copy R, cast Rb, np-pairwise r2);
// blocks [4096,8192) handle codebook rows (cast Cbb, np-pairwise c2).
__global__ __launch_bounds__(256) void k_initnorm(
        const float* __restrict__ x, const float* __restrict__ cbs,
        float4* __restrict__ R, ushort4* __restrict__ Rb, ushort4* __restrict__ Cbb,
        float* __restrict__ r2, float* __restrict__ c2)
{
#pragma clang fp contract(off)
    __shared__ float buf[4][DIM];
    __shared__ float accs[4][32];
    const int w = threadIdx.x >> 6, lane = threadIdx.x & 63;
    const bool isX = blockIdx.x < (NTOK / 4);
    const int row = (isX ? blockIdx.x : blockIdx.x - NTOK / 4) * 4 + w;

    const float* src = isX ? x : cbs;
    const float4* a4 = reinterpret_cast<const float4*>(src + (size_t)row * DIM);
    float4 v0 = a4[lane], v1 = a4[lane + 64];

    ushort4 b0 = make_ushort4(f2bf(v0.x), f2bf(v0.y), f2bf(v0.z), f2bf(v0.w));
    ushort4 b1 = make_ushort4(f2bf(v1.x), f2bf(v1.y), f2bf(v1.z), f2bf(v1.w));
    if (isX) {
        R [(size_t)row * 128 + lane]      = v0;
        R [(size_t)row * 128 + lane + 64] = v1;
        Rb[(size_t)row * 128 + lane]      = b0;
        Rb[(size_t)row * 128 + lane + 64] = b1;
    } else {
        Cbb[(size_t)row * 128 + lane]      = b0;
        Cbb[(size_t)row * 128 + lane + 64] = b1;
    }

    float4* b4 = reinterpret_cast<float4*>(buf[w]);
    b4[lane]      = v0;
    b4[lane + 64] = v1;
    __syncthreads();
    if (lane < 32) {
        int blk = lane >> 3, j = lane & 7;
        const float* p = buf[w] + blk * 128 + j;
        float x0 = p[0];
        float acc = x0 * x0;
#pragma unroll
        for (int m = 1; m < 16; ++m) { float xx = p[8 * m]; acc = acc + xx * xx; }
        accs[w][lane] = acc;
    }
    __syncthreads();
    if (lane == 0) {
        float B[4];
#pragma unroll
        for (int blk = 0; blk < 4; ++blk) {
            const float* r = &accs[w][blk * 8];
            B[blk] = ((r[0] + r[1]) + (r[2] + r[3])) + ((r[4] + r[5]) + (r[6] + r[7]));
        }
        float out = (B[0] + B[1]) + (B[2] + B[3]);
        if (isX) r2[row] = out; else c2[row] = out;
    }
}

// 256x256 tile bf16 MFMA GEMM (A.B^T) + per-row top-4 per 128-col block.
// BK=64, 2-buffer drain K-loop (8 iters). 8 waves (2Mx4N), each 128x64 out.
__global__ __launch_bounds__(512, 2) void k_gemm_topk(
        const unsigned short* __restrict__ Rb, const unsigned short* __restrict__ Cbb,
        const float* __restrict__ c2, float* __restrict__ candS, int* __restrict__ candI)
{
    // A bufs: [0,65536) = A0|A1 (32KB each, 16 units of 2KB: unit g = rows
    // g*16..+15, layout [half(512sh)][lane*8sh]). B bufs: [65536,131072).
    // scb fp32 [64][260] aliases staging post-K-loop (66560B).
    // c2s skewed (288 floats) at 131072. Total 132224 -> 1 block/CU.
    __shared__ __align__(16) char smem[132224];
    unsigned short* As = (unsigned short*)smem;
    unsigned short* Bs = (unsigned short*)(smem + 65536);
    float*  scb = (float*)smem;
    float*  c2s = (float*)(smem + 131072);

    const int tid  = threadIdx.x;
    const int wid  = tid >> 6, lane = tid & 63;
    const int quad = lane >> 4, l16 = lane & 15;
    const int wr = wid >> 2, wc = wid & 3;

    // XCD pinning: L%8 = HW XCD round-robin; each XCD owns 8 row-panels,
    // col-tile nb2 iterates fastest. Bijective on [0,512).
    const int L    = blockIdx.y * NBLK2 + blockIdx.x;
    const int slot = L >> 3;
    const int mb   = (L & 7) * 8 + (slot >> 3);   // 0..63 row panel
    const int nb2  = slot & 7;                    // 0..7 col tile (256 wide)

    const int tok0 = mb * 256, n0 = nb2 * 256;

    // skewed c2s: float col c stored at c + 4*(c>>5) -> the epilogue's 4j
    // chunk reads spread over banks (was ALL in bank 4j: the 786-917K confl).
    if (tid < 256) c2s[tid + 4 * (tid >> 5)] = c2[n0 + tid];

    float4v acc[8][4];
    float4v zero = {0.f, 0.f, 0.f, 0.f};
#pragma unroll
    for (int mi = 0; mi < 8; ++mi)
#pragma unroll
        for (int nj = 0; nj < 4; ++nj) acc[mi][nj] = zero;

    // stage K-tile kb (64 wide) into buffer b: wave wid owns units
    // {wid*2, wid*2+1} of A and B; per unit 2 gl2lds (k-halves 0,1).
    // Unit g: lane (quad,l16) loads row g*16+l16, k = kb + h*32 + quad*8
    // -> LDS g*1024 + h*512 shorts (+lane*8 HW).
    auto stage = [&](int b, int kb) {
        unsigned short* Ad = As + b * 16384;
        unsigned short* Bd = Bs + b * 16384;
#pragma unroll
        for (int c = 0; c < 2; ++c) {
            int g = wid * 2 + c;
#pragma unroll
            for (int h = 0; h < 2; ++h)
                gl2lds16(&Rb[(size_t)(tok0 + g * 16 + l16) * DIM + kb + h * 32 + quad * 8],
                         Ad + (size_t)g * 1024 + h * 512);
        }
#pragma unroll
        for (int c = 0; c < 2; ++c) {
            int g = wid * 2 + c;
#pragma unroll
            for (int h = 0; h < 2; ++h)
                gl2lds16(&Cbb[(size_t)(n0 + g * 16 + l16) * DIM + kb + h * 32 + quad * 8],
                         Bd + (size_t)g * 1024 + h * 512);
        }
    };

    // compute BK=64: kk=0 then kk=1 (k globally ascending -> bit-identical
    // accumulation chain per acc[mi][nj]).
    auto compute = [&](int b) {
        const unsigned short* Ac = As + b * 16384;
        const unsigned short* Bc = Bs + b * 16384;
#pragma unroll
        for (int kk = 0; kk < 2; ++kk) {
            short8 af[8], bf[4];
#pragma unroll
            for (int mi = 0; mi < 8; ++mi)
                af[mi] = *(const short8*)(Ac + (size_t)(wr * 8 + mi) * 1024 + kk * 512 + lane * 8);
#pragma unroll
            for (int nj = 0; nj < 4; ++nj)
                bf[nj] = *(const short8*)(Bc + (size_t)(wc * 4 + nj) * 1024 + kk * 512 + lane * 8);
            __builtin_amdgcn_s_setprio(1);             // T5
#pragma unroll
            for (int mi = 0; mi < 8; ++mi)
#pragma unroll
                for (int nj = 0; nj < 4; ++nj)
                    acc[mi][nj] = __builtin_amdgcn_mfma_f32_16x16x32_bf16(
                        af[mi], bf[nj], acc[mi][nj], 0, 0, 0);
            __builtin_amdgcn_s_setprio(0);
        }
    };

    // K-loop: R9-proven drain pattern (__syncthreads drains vmcnt before
    // s_barrier -> buf staged at it-1 ready; staging buf (it+1)&1 safe since
    // all waves finished reading it at it-1).
    stage(0, 0);
    for (int it = 0; it < 8; ++it) {
        __syncthreads();
        if (it < 7) stage((it + 1) & 1, (it + 1) * 64);
        compute(it & 1);
    }

    // epilogue (R12-identical structure): 4 row-quarters of 64x256 via scb
    // stride 260. Writes 2 lanes/bank; b128 reads uniform 8-residue spread.
    // Thread (row=tid>>3, pp=tid&7): block pp>>2, part pp&3 owns 32
    // contiguous cols; ascending scan + xor(1,2) merge (validated discipline).
    const int row_ = tid >> 3, pp = tid & 7;
    float4 c2r[8];
#pragma unroll
    for (int j = 0; j < 8; ++j)
        c2r[j] = *(const float4*)(c2s + pp * 36 + 4 * j);   // skew: (pp*32+4j)+4*pp

#pragma unroll
    for (int qr = 0; qr < 4; ++qr) {
        __syncthreads();
        if (wr == (qr >> 1)) {
            const int mi0 = (qr & 1) * 4;
#pragma unroll
            for (int mm = 0; mm < 4; ++mm)
#pragma unroll
                for (int nj = 0; nj < 4; ++nj) {
                    int r0 = mm * 16 + quad * 4;
                    int cc = wc * 64 + nj * 16 + l16;
#pragma unroll
                    for (int e = 0; e < 4; ++e)
                        scb[(r0 + e) * 260 + cc] = acc[mi0 + mm][nj][e];
                }
        }
        __syncthreads();
        Top4 t; t4_init(t);
#pragma unroll
        for (int j = 0; j < 8; ++j) {
            float4 sv = *(const float4*)(scb + row_ * 260 + pp * 32 + 4 * j);
            float4 cv = c2r[j];
            int c0 = n0 + pp * 32 + 4 * j;
            t4_ins(t, cv.x - 2.0f * sv.x, c0 + 0);
            t4_ins(t, cv.y - 2.0f * sv.y, c0 + 1);
            t4_ins(t, cv.z - 2.0f * sv.z, c0 + 2);
            t4_ins(t, cv.w - 2.0f * sv.w, c0 + 3);
        }
        // merge the 4 parts of this (row, 128-block) via xor shuffles
#pragma unroll
        for (int k = 1; k <= 2; k <<= 1) {
            float os[4]; int oi[4];
#pragma unroll
            for (int j = 0; j < 4; ++j) {
                os[j] = __shfl_xor(t.s[j], k, 64);
                oi[j] = __shfl_xor(t.i[j], k, 64);
            }
#pragma unroll
            for (int j = 0; j < 4; ++j) t4_ins(t, os[j], oi[j]);
        }
        if ((pp & 3) == 0) {
            int token = tok0 + qr * 64 + row_;
            int nb = nb2 * 2 + (pp >> 2);
            size_t base = (size_t)token * 64 + (size_t)nb * 4;
#pragma unroll
            for (int j = 0; j < 4; ++j) { candS[base + j] = t.s[j]; candI[base + j] = t.i[j]; }
        }
    }
}

// Fused: select winner (R3-replica exact rescore of in-window candidates),
// update residual, recast bf16, np-ordered r2 for next level, loss partial.
__global__ __launch_bounds__(256) void k_selupd(
        const float* __restrict__ candS, const int* __restrict__ candI,
        float* __restrict__ R, const float* __restrict__ cbf,
        float* __restrict__ r2, const float* __restrict__ c2,
        float* __restrict__ idx_out, float* __restrict__ partial,
        ushort4* __restrict__ Rb, const float4* __restrict__ x, int level)
{
#pragma clang fp contract(off)
    __shared__ float buf[4][DIM];
    __shared__ float accs[4][32];
    __shared__ float shl[4];
    const int w = threadIdx.x >> 6, lane = threadIdx.x & 63;
    const int t = blockIdx.x * 4 + w;
    const bool last = (level == NQ - 1);

    // ---- stage R row (coalesced) into regs + per-wave LDS copy ----
    float4* r4 = reinterpret_cast<float4*>(R + (size_t)t * DIM);
    float4* b4 = reinterpret_cast<float4*>(buf[w]);
    float4 rr[2];
    rr[0] = r4[lane];      rr[1] = r4[lane + 64];
    b4[lane] = rr[0];      b4[lane + 64] = rr[1];

    // ---- select ----
    float sb = candS[(size_t)t * 64 + lane];
    int   ci = candI[(size_t)t * 64 + lane];
    float mn = sb;
#pragma unroll
    for (int off = 32; off; off >>= 1) mn = fminf(mn, __shfl_xor(mn, off, 64));
    unsigned long long mask = __ballot(sb <= mn + WINDOW);
    int ncand = __popcll(mask);
    int winner;
    if (ncand == 1) {
        winner = __shfl(ci, __ffsll(mask) - 1, 64);
    } else {
        int src = 0;
        if (lane < ncand) {
            unsigned long long mm = mask;
            for (int z = 0; z < lane; ++z) mm &= mm - 1;
            src = __ffsll(mm) - 1;
        }
        int cidx = __shfl(ci, src, 64);
        float s = 3.0e38f;
        int   si = 0x7FFFFFFF;
        if (lane < ncand) {
            const float4* cp4 = reinterpret_cast<const float4*>(cbf + (size_t)cidx * DIM);
            const float4* rp4 = reinterpret_cast<const float4*>(buf[w]);  // broadcast
            float d = 0.f;
#pragma unroll 4
            for (int j = 0; j < DIM / 4; ++j) {
                float4 cv = cp4[j];
                float4 rv = rp4[j];
                d = fmaf(rv.x, cv.x, d);
                d = fmaf(rv.y, cv.y, d);
                d = fmaf(rv.z, cv.z, d);
                d = fmaf(rv.w, cv.w, d);
            }
            float td = 2.0f * d;
            float a  = r2[t] - td;
            s  = a + c2[cidx];
            si = cidx;
        }
#pragma unroll
        for (int off = 32; off; off >>= 1) {
            float ov = __shfl_xor(s, off, 64);
            int   oi = __shfl_xor(si, off, 64);
            if (ov < s || (ov == s && oi < si)) { s = ov; si = oi; }
        }
        winner = si;
    }
    if (lane == 0) idx_out[(size_t)t * NQ + level] = (float)winner;

    // ---- update (reuses staged rr; values identical to re-reading R) ----
    const float4* c4 = reinterpret_cast<const float4*>(cbf + (size_t)winner * DIM);
    float ls = 0.f;
#pragma unroll
    for (int i = 0; i < 2; ++i) {
        int d = lane + 64 * i;
        float4 rv = rr[i], cv = c4[d];
        rv.x -= cv.x; rv.y -= cv.y; rv.z -= cv.z; rv.w -= cv.w;
        ls = ls + rv.x * rv.x; ls = ls + rv.y * rv.y;
        ls = ls + rv.z * rv.z; ls = ls + rv.w * rv.w;
        if (!last) {
            r4[d] = rv;
            b4[d] = rv;
            Rb[(size_t)t * 128 + d] = make_ushort4(f2bf(rv.x), f2bf(rv.y),
                                                   f2bf(rv.z), f2bf(rv.w));
        } else {
            float4 xv = x[(size_t)t * 128 + d];
            xv.x -= rv.x; xv.y -= rv.y; xv.z -= rv.z; xv.w -= rv.w;
            r4[d] = xv;                       // quantized = x - r_final (in d_out)
        }
    }

    if (!last) {
        __syncthreads();
        // np-pairwise r2 of the NEW residual (same order as k_initnorm)
        if (lane < 32) {
            int blk = lane >> 3, j = lane & 7;
            const float* p = buf[w] + blk * 128 + j;
            float x0 = p[0];
            float acc = x0 * x0;
#pragma unroll
            for (int m = 1; m < 16; ++m) { float xx = p[8 * m]; acc = acc + xx * xx; }
            accs[w][lane] = acc;
        }
        __syncthreads();
        if (lane == 0) {
            float B[4];
#pragma unroll
            for (int blk = 0; blk < 4; ++blk) {
                const float* r = &accs[w][blk * 8];
                B[blk] = ((r[0] + r[1]) + (r[2] + r[3])) + ((r[4] + r[5]) + (r[6] + r[7]));
            }
            r2[t] = (B[0] + B[1]) + (B[2] + B[3]);
        }
    }

    // ---- loss partial ----
#pragma unroll
    for (int off = 32; off; off >>= 1) ls += __shfl_down(ls, off, 64);
    if (lane == 0) shl[w] = ls;
    __syncthreads();
    if (threadIdx.x == 0) partial[blockIdx.x] = (shl[0] + shl[1]) + (shl[2] + shl[3]);
}

__global__ __launch_bounds__(256) void k_finalize_loss(const float* __restrict__ partial,
                                                       float* __restrict__ loss_out)
{
    double s = 0.0;
    for (int i = threadIdx.x; i < NQ * (NTOK / 4); i += 256) s += (double)partial[i];
#pragma unroll
    for (int off = 32; off; off >>= 1) s += __shfl_down(s, off, 64);
    __shared__ double sh[4];
    if ((threadIdx.x & 63) == 0) sh[threadIdx.x >> 6] = s;
    __syncthreads();
    if (threadIdx.x == 0) {
        double tot = (sh[0] + sh[1]) + (sh[2] + sh[3]);
        loss_out[0] = (float)(tot * 1.25 / ((double)NQ * (double)QELEM));
    }
}

extern "C" void kernel_launch(void* const* d_in, const int* in_sizes, int n_in,
                              void* d_out, int out_size, void* d_ws, size_t ws_size,
                              hipStream_t stream)
{
    const float* x   = (const float*)d_in[0];
    const float* cbs = (const float*)d_in[1];

    float* qout     = (float*)d_out;
    float* idx_out  = qout + QELEM;
    float* loss_out = idx_out + (size_t)NTOK * NQ;
    float* R        = qout;                 // residual lives in d_out (validated R5)

    char* ws = (char*)d_ws;
    size_t off = 0;
    unsigned short* Rb   = (unsigned short*)(ws + off); off += (size_t)QELEM * 2;  // 16MB
    unsigned short* Cbb  = (unsigned short*)(ws + off); off += (size_t)QELEM * 2;  // 16MB
    float*          c2   = (float*)(ws + off);          off += (size_t)NQ * KCB * 4;
    float*          r2   = (float*)(ws + off);          off += (size_t)NTOK * 4;
    float*          part = (float*)(ws + off);          off += (size_t)NQ * (NTOK / 4) * 4;
    float*          candS= (float*)(ws + off);          off += (size_t)NTOK * 64 * 4; // 4MB
    int*            candI= (int*)(ws + off);            off += (size_t)NTOK * 64 * 4; // 4MB

    // fused init: x rows (R copy, Rb cast, r2) + cb rows (Cbb cast, c2)
    k_initnorm<<<NTOK / 4 + NQ * KCB / 4, 256, 0, stream>>>(
        x, cbs, (float4*)R, (ushort4*)Rb, (ushort4*)Cbb, r2, c2);

    for (int q = 0; q < NQ; ++q) {
        const float*          cbq  = cbs + (size_t)q * KCB * DIM;
        const unsigned short* cbbq = Cbb + (size_t)q * KCB * DIM;
        const float*          c2q  = c2 + (size_t)q * KCB;
        dim3 g(NBLK2, NTOK / 256);
        k_gemm_topk<<<g, 512, 0, stream>>>(Rb, cbbq, c2q, candS, candI);
        k_selupd<<<NTOK / 4, 256, 0, stream>>>(candS, candI, R, cbq, r2, c2q,
                                               idx_out, part + (size_t)q * (NTOK / 4),
                                               (ushort4*)Rb, (const float4*)x, q);
    }

    k_finalize_loss<<<1, 256, 0, stream>>>(part, loss_out);
}

// Round 7
// 988.781 us; speedup vs baseline: 1.2985x; 1.0386x over previous
//
#include <hip/hip_runtime.h>

// Residual VQ forward, MFMA candidates + R3-replica exact selection. R15:
//  - k_gemm_topk: m201-style fine per-phase interleave on the R12 geometry.
//    256x256, BK=32, 3 LDS buffers (96KB), 2 phases per K-tile:
//    {ds_read (8|4 b128) ; stage 2 gl2lds ; lgkmcnt(0)+sched_barrier ;
//     setprio(1) ; 16 MFMA ; setprio(0) ; s_barrier}. Counted vmcnt(4) at
//    iter top (R12's exact 4-loads/iter FIFO ledger; last iter vmcnt(0)).
//    Rationale: all coarse variants (R10-R14) land at ~23k CU-cyc per
//    128^2-unit regardless of occupancy/BK/buffering -> m196's lesson:
//    the per-phase ds||stage||MFMA interleave is the lever, coarse is null.
//  - epilogue + c2s skew verbatim R14 (validated; residual 524K conflicts =
//    scb b128 structural 8-beat minimum, ~0.85us -> ignored).
// Per-fragment MFMA order ascending-k on identical operands -> scores
// BIT-IDENTICAL; candidate discipline unchanged.
// R12: 256^2 geometry. R11: fused init, b128 epilogue, setprio. R10: selupd
// coalesced staging. R9: XCD-pinned swizzle (FETCH ideal).
// d_out flat: [quantized (B,T,D) | indices (B,T,Q) as float | loss scalar]
// Selection arithmetic (validated R3/R5/R6/R7, bit-exact vs reference):
//   sb = c2 - 2*dot_bf16 candidates (top-4 per 128-code block);
//   exact rescore = ascending 512-step fmaf chain, s = fl(fl(r2-2d)+c2),
//   contract off, lowest-index tie-break; r2/c2 numpy-pairwise order.

constexpr int DIM   = 512;
constexpr int KCB   = 2048;
constexpr int NQ    = 8;
constexpr int NTOK  = 8 * 2048;       // 16384
constexpr int QELEM = NTOK * DIM;     // 8388608
constexpr int NBLK2 = KCB / 256;      // 8 column tiles (256 wide)
constexpr float WINDOW = 1e-3f;       // worst-case bf16 score err ~4.5e-4

using short8  = __attribute__((ext_vector_type(8))) short;
using float4v = __attribute__((ext_vector_type(4))) float;

__device__ __forceinline__ unsigned short f2bf(float f) {
    unsigned u = __float_as_uint(f);
    return (unsigned short)((u + 0x7FFFu + ((u >> 16) & 1u)) >> 16);   // RNE
}

__device__ __forceinline__ void gl2lds16(const void* g, void* l) {
    __builtin_amdgcn_global_load_lds(
        (__attribute__((address_space(1))) void*)g,
        (__attribute__((address_space(3))) void*)l, 16, 0, 0);
}

struct Top4 { float s[4]; int i[4]; };
__device__ __forceinline__ void t4_init(Top4& t) {
#pragma unroll
    for (int j = 0; j < 4; ++j) { t.s[j] = 3.0e38f; t.i[j] = 0x7FFFFFFF; }
}
__device__ __forceinline__ void t4_ins(Top4& t, float s, int idx) {
    if (s < t.s[3]) {
        if (s < t.s[2]) { t.s[3] = t.s[2]; t.i[3] = t.i[2];
            if (s < t.s[1]) { t.s[2] = t.s[1]; t.i[2] = t.i[1];
                if (s < t.s[0]) { t.s[1] = t.s[0]; t.i[1] = t.i[0]; t.s[0] = s; t.i[0] = idx; }
                else            { t.s[1] = s; t.i[1] = idx; }
            } else { t.s[2] = s; t.i[2] = idx; }
        } else { t.s[3] = s; t.i[3] = idx; }
    }
}

// Fused init: blocks [0,4096) handle x rows (copy R, cast Rb, np-pairwise r2);
// blocks [4096,8192) handle codebook rows (cast Cbb, np-pairwise c2).
__global__ __launch_bounds__(256) void k_initnorm(
        const float* __restrict__ x, const float* __restrict__ cbs,
        float4* __restrict__ R, ushort4* __restrict__ Rb, ushort4* __restrict__ Cbb,
        float* __restrict__ r2, float* __restrict__ c2)
{
#pragma clang fp contract(off)
    __shared__ float buf[4][DIM];
    __shared__ float accs[4][32];
    const int w = threadIdx.x >> 6, lane = threadIdx.x & 63;
    const bool isX = blockIdx.x < (NTOK / 4);
    const int row = (isX ? blockIdx.x : blockIdx.x - NTOK / 4) * 4 + w;

    const float* src = isX ? x : cbs;
    const float4* a4 = reinterpret_cast<const float4*>(src + (size_t)row * DIM);
    float4 v0 = a4[lane], v1 = a4[lane + 64];

    ushort4 b0 = make_ushort4(f2bf(v0.x), f2bf(v0.y), f2bf(v0.z), f2bf(v0.w));
    ushort4 b1 = make_ushort4(f2bf(v1.x), f2bf(v1.y), f2bf(v1.z), f2bf(v1.w));
    if (isX) {
        R [(size_t)row * 128 + lane]      = v0;
        R [(size_t)row * 128 + lane + 64] = v1;
        Rb[(size_t)row * 128 + lane]      = b0;
        Rb[(size_t)row * 128 + lane + 64] = b1;
    } else {
        Cbb[(size_t)row * 128 + lane]      = b0;
        Cbb[(size_t)row * 128 + lane + 64] = b1;
    }

    float4* b4 = reinterpret_cast<float4*>(buf[w]);
    b4[lane]      = v0;
    b4[lane + 64] = v1;
    __syncthreads();
    if (lane < 32) {
        int blk = lane >> 3, j = lane & 7;
        const float* p = buf[w] + blk * 128 + j;
        float x0 = p[0];
        float acc = x0 * x0;
#pragma unroll
        for (int m = 1; m < 16; ++m) { float xx = p[8 * m]; acc = acc + xx * xx; }
        accs[w][lane] = acc;
    }
    __syncthreads();
    if (lane == 0) {
        float B[4];
#pragma unroll
        for (int blk = 0; blk < 4; ++blk) {
            const float* r = &accs[w][blk * 8];
            B[blk] = ((r[0] + r[1]) + (r[2] + r[3])) + ((r[4] + r[5]) + (r[6] + r[7]));
        }
        float out = (B[0] + B[1]) + (B[2] + B[3]);
        if (isX) r2[row] = out; else c2[row] = out;
    }
}

// 256x256 tile bf16 MFMA GEMM (A.B^T) + per-row top-4 per 128-col block.
// BK=32, 3-buffer, fine 2-phase-per-tile interleave with counted vmcnt.
// 8 waves (2Mx4N), each 128x64 out.
__global__ __launch_bounds__(512, 2) void k_gemm_topk(
        const unsigned short* __restrict__ Rb, const unsigned short* __restrict__ Cbb,
        const float* __restrict__ c2, float* __restrict__ candS, int* __restrict__ candI)
{
    // A bufs: [0,49152) = 3 x 16KB (16 units of 1KB: unit g = rows g*16..+15,
    // lane*16B linear). B bufs: [49152,98304). c2s skewed (288 fl) at 98304.
    // scb fp32 [64][260] aliases staging post-K-loop (66560B). Total 99456.
    __shared__ __align__(16) char smem[99456];
    unsigned short* As = (unsigned short*)smem;
    unsigned short* Bs = (unsigned short*)(smem + 49152);
    float*  scb = (float*)smem;
    float*  c2s = (float*)(smem + 98304);

    const int tid  = threadIdx.x;
    const int wid  = tid >> 6, lane = tid & 63;
    const int quad = lane >> 4, l16 = lane & 15;
    const int wr = wid >> 2, wc = wid & 3;

    // XCD pinning: L%8 = HW XCD round-robin; each XCD owns 8 row-panels,
    // col-tile nb2 iterates fastest. Bijective on [0,512).
    const int L    = blockIdx.y * NBLK2 + blockIdx.x;
    const int slot = L >> 3;
    const int mb   = (L & 7) * 8 + (slot >> 3);   // 0..63 row panel
    const int nb2  = slot & 7;                    // 0..7 col tile (256 wide)

    const int tok0 = mb * 256, n0 = nb2 * 256;

    // skewed c2s: float col c stored at c + 4*(c>>5)
    if (tid < 256) c2s[tid + 4 * (tid >> 5)] = c2[n0 + tid];

    float4v acc[8][4];
    float4v zero = {0.f, 0.f, 0.f, 0.f};
#pragma unroll
    for (int mi = 0; mi < 8; ++mi)
#pragma unroll
        for (int nj = 0; nj < 4; ++nj) acc[mi][nj] = zero;

    // stage K-tile kb (32 wide) into buffer b, split A/B (2 gl2lds each):
    // wave wid owns units {wid*2, wid*2+1}; unit g: lane (quad,l16) loads
    // row g*16+l16, k = kb+quad*8 -> LDS g*512 shorts (+lane*16B HW).
    auto stageA = [&](int b, int kb) {
        unsigned short* Ad = As + b * 8192;
#pragma unroll
        for (int c = 0; c < 2; ++c) {
            int g = wid * 2 + c;
            gl2lds16(&Rb[(size_t)(tok0 + g * 16 + l16) * DIM + kb + quad * 8],
                     Ad + (size_t)g * 512);
        }
    };
    auto stageB = [&](int b, int kb) {
        unsigned short* Bd = Bs + b * 8192;
#pragma unroll
        for (int c = 0; c < 2; ++c) {
            int g = wid * 2 + c;
            gl2lds16(&Cbb[(size_t)(n0 + g * 16 + l16) * DIM + kb + quad * 8],
                     Bd + (size_t)g * 512);
        }
    };

    // K-loop ledger (= R12's, proven): 4 gl2lds issued per iter (2 in each
    // phase). At iter top outstanding <= 8 (tiles it, it+1); vmcnt(4) =>
    // tile it landed; barrier => for all waves. Staging target (it+2)%3 is
    // the buffer whose reads finished at it-1 (barriers order this).
    stageA(0, 0);  stageB(0, 0);
    stageA(1, 32); stageB(1, 32);
    int cur = 0, pf = 2;
    for (int it = 0; it < 16; ++it) {
        if (it < 15) asm volatile("s_waitcnt vmcnt(4)" ::: "memory");
        else         asm volatile("s_waitcnt vmcnt(0)" ::: "memory");
        __builtin_amdgcn_s_barrier();
        __builtin_amdgcn_sched_barrier(0);

        const unsigned short* Ac = As + cur * 8192;
        const unsigned short* Bc = Bs + cur * 8192;

        // ---- phase 0: bf + af(mi 0..3) reads, stage A(it+2), MFMA mi 0..3
        short8 bf[4], af[4];
#pragma unroll
        for (int nj = 0; nj < 4; ++nj)
            bf[nj] = *(const short8*)(Bc + (size_t)(wc * 4 + nj) * 512 + lane * 8);
#pragma unroll
        for (int m = 0; m < 4; ++m)
            af[m] = *(const short8*)(Ac + (size_t)(wr * 8 + m) * 512 + lane * 8);
        if (it < 14) stageA(pf, (it + 2) * 32);
        asm volatile("s_waitcnt lgkmcnt(0)" ::: "memory");
        __builtin_amdgcn_sched_barrier(0);
        __builtin_amdgcn_s_setprio(1);
#pragma unroll
        for (int m = 0; m < 4; ++m)
#pragma unroll
            for (int nj = 0; nj < 4; ++nj)
                acc[m][nj] = __builtin_amdgcn_mfma_f32_16x16x32_bf16(
                    af[m], bf[nj], acc[m][nj], 0, 0, 0);
        __builtin_amdgcn_s_setprio(0);
        __builtin_amdgcn_s_barrier();
        __builtin_amdgcn_sched_barrier(0);

        // ---- phase 1: af(mi 4..7) reads, stage B(it+2), MFMA mi 4..7
        short8 af2[4];
#pragma unroll
        for (int m = 0; m < 4; ++m)
            af2[m] = *(const short8*)(Ac + (size_t)(wr * 8 + 4 + m) * 512 + lane * 8);
        if (it < 14) stageB(pf, (it + 2) * 32);
        asm volatile("s_waitcnt lgkmcnt(0)" ::: "memory");
        __builtin_amdgcn_sched_barrier(0);
        __builtin_amdgcn_s_setprio(1);
#pragma unroll
        for (int m = 0; m < 4; ++m)
#pragma unroll
            for (int nj = 0; nj < 4; ++nj)
                acc[4 + m][nj] = __builtin_amdgcn_mfma_f32_16x16x32_bf16(
                    af2[m], bf[nj], acc[4 + m][nj], 0, 0, 0);
        __builtin_amdgcn_s_setprio(0);

        cur = (cur == 2) ? 0 : cur + 1;
        pf  = (pf  == 2) ? 0 : pf  + 1;
    }

    // epilogue (verbatim R14, validated): 4 row-quarters of 64x256 via scb
    // stride 260. Thread (row=tid>>3, pp=tid&7): block pp>>2, part pp&3 owns
    // 32 contiguous cols; ascending scan + xor(1,2) merge.
    const int row_ = tid >> 3, pp = tid & 7;
    float4 c2r[8];
#pragma unroll
    for (int j = 0; j < 8; ++j)
        c2r[j] = *(const float4*)(c2s + pp * 36 + 4 * j);   // skew: (pp*32+4j)+4*pp

#pragma unroll
    for (int qr = 0; qr < 4; ++qr) {
        __syncthreads();
        if (wr == (qr >> 1)) {
            const int mi0 = (qr & 1) * 4;
#pragma unroll
            for (int mm = 0; mm < 4; ++mm)
#pragma unroll
                for (int nj = 0; nj < 4; ++nj) {
                    int r0 = mm * 16 + quad * 4;
                    int cc = wc * 64 + nj * 16 + l16;
#pragma unroll
                    for (int e = 0; e < 4; ++e)
                        scb[(r0 + e) * 260 + cc] = acc[mi0 + mm][nj][e];
                }
        }
        __syncthreads();
        Top4 t; t4_init(t);
#pragma unroll
        for (int j = 0; j < 8; ++j) {
            float4 sv = *(const float4*)(scb + row_ * 260 + pp * 32 + 4 * j);
            float4 cv = c2r[j];
            int c0 = n0 + pp * 32 + 4 * j;
            t4_ins(t, cv.x - 2.0f * sv.x, c0 + 0);
            t4_ins(t, cv.y - 2.0f * sv.y, c0 + 1);
            t4_ins(t, cv.z - 2.0f * sv.z, c0 + 2);
            t4_ins(t, cv.w - 2.0f * sv.w, c0 + 3);
        }
        // merge the 4 parts of this (row, 128-block) via xor shuffles
#pragma unroll
        for (int k = 1; k <= 2; k <<= 1) {
            float os[4]; int oi[4];
#pragma unroll
            for (int j = 0; j < 4; ++j) {
                os[j] = __shfl_xor(t.s[j], k, 64);
                oi[j] = __shfl_xor(t.i[j], k, 64);
            }
#pragma unroll
            for (int j = 0; j < 4; ++j) t4_ins(t, os[j], oi[j]);
        }
        if ((pp & 3) == 0) {
            int token = tok0 + qr * 64 + row_;
            int nb = nb2 * 2 + (pp >> 2);
            size_t base = (size_t)token * 64 + (size_t)nb * 4;
#pragma unroll
            for (int j = 0; j < 4; ++j) { candS[base + j] = t.s[j]; candI[base + j] = t.i[j]; }
        }
    }
}

// Fused: select winner (R3-replica exact rescore of in-window candidates),
// update residual, recast bf16, np-ordered r2 for next level, loss partial.
__global__ __launch_bounds__(256) void k_selupd(
        const float* __restrict__ candS, const int* __restrict__ candI,
        float* __restrict__ R, const float* __restrict__ cbf,
        float* __restrict__ r2, const float* __restrict__ c2,
        float* __restrict__ idx_out, float* __restrict__ partial,
        ushort4* __restrict__ Rb, const float4* __restrict__ x, int level)
{
#pragma clang fp contract(off)
    __shared__ float buf[4][DIM];
    __shared__ float accs[4][32];
    __shared__ float shl[4];
    const int w = threadIdx.x >> 6, lane = threadIdx.x & 63;
    const int t = blockIdx.x * 4 + w;
    const bool last = (level == NQ - 1);

    // ---- stage R row (coalesced) into regs + per-wave LDS copy ----
    float4* r4 = reinterpret_cast<float4*>(R + (size_t)t * DIM);
    float4* b4 = reinterpret_cast<float4*>(buf[w]);
    float4 rr[2];
    rr[0] = r4[lane];      rr[1] = r4[lane + 64];
    b4[lane] = rr[0];      b4[lane + 64] = rr[1];

    // ---- select ----
    float sb = candS[(size_t)t * 64 + lane];
    int   ci = candI[(size_t)t * 64 + lane];
    float mn = sb;
#pragma unroll
    for (int off = 32; off; off >>= 1) mn = fminf(mn, __shfl_xor(mn, off, 64));
    unsigned long long mask = __ballot(sb <= mn + WINDOW);
    int ncand = __popcll(mask);
    int winner;
    if (ncand == 1) {
        winner = __shfl(ci, __ffsll(mask) - 1, 64);
    } else {
        int src = 0;
        if (lane < ncand) {
            unsigned long long mm = mask;
            for (int z = 0; z < lane; ++z) mm &= mm - 1;
            src = __ffsll(mm) - 1;
        }
        int cidx = __shfl(ci, src, 64);
        float s = 3.0e38f;
        int   si = 0x7FFFFFFF;
        if (lane < ncand) {
            const float4* cp4 = reinterpret_cast<const float4*>(cbf + (size_t)cidx * DIM);
            const float4* rp4 = reinterpret_cast<const float4*>(buf[w]);  // broadcast
            float d = 0.f;
#pragma unroll 4
            for (int j = 0; j < DIM / 4; ++j) {
                float4 cv = cp4[j];
                float4 rv = rp4[j];
                d = fmaf(rv.x, cv.x, d);
                d = fmaf(rv.y, cv.y, d);
                d = fmaf(rv.z, cv.z, d);
                d = fmaf(rv.w, cv.w, d);
            }
            float td = 2.0f * d;
            float a  = r2[t] - td;
            s  = a + c2[cidx];
            si = cidx;
        }
#pragma unroll
        for (int off = 32; off; off >>= 1) {
            float ov = __shfl_xor(s, off, 64);
            int   oi = __shfl_xor(si, off, 64);
            if (ov < s || (ov == s && oi < si)) { s = ov; si = oi; }
        }
        winner = si;
    }
    if (lane == 0) idx_out[(size_t)t * NQ + level] = (float)winner;

    // ---- update (reuses staged rr; values identical to re-reading R) ----
    const float4* c4 = reinterpret_cast<const float4*>(cbf + (size_t)winner * DIM);
    float ls = 0.f;
#pragma unroll
    for (int i = 0; i < 2; ++i) {
        int d = lane + 64 * i;
        float4 rv = rr[i], cv = c4[d];
        rv.x -= cv.x; rv.y -= cv.y; rv.z -= cv.z; rv.w -= cv.w;
        ls = ls + rv.x * rv.x; ls = ls + rv.y * rv.y;
        ls = ls + rv.z * rv.z; ls = ls + rv.w * rv.w;
        if (!last) {
            r4[d] = rv;
            b4[d] = rv;
            Rb[(size_t)t * 128 + d] = make_ushort4(f2bf(rv.x), f2bf(rv.y),
                                                   f2bf(rv.z), f2bf(rv.w));
        } else {
            float4 xv = x[(size_t)t * 128 + d];
            xv.x -= rv.x; xv.y -= rv.y; xv.z -= rv.z; xv.w -= rv.w;
            r4[d] = xv;                       // quantized = x - r_final (in d_out)
        }
    }

    if (!last) {
        __syncthreads();
        // np-pairwise r2 of the NEW residual (same order as k_initnorm)
        if (lane < 32) {
            int blk = lane >> 3, j = lane & 7;
            const float* p = buf[w] + blk * 128 + j;
            float x0 = p[0];
            float acc = x0 * x0;
#pragma unroll
            for (int m = 1; m < 16; ++m) { float xx = p[8 * m]; acc = acc + xx * xx; }
            accs[w][lane] = acc;
        }
        __syncthreads();
        if (lane == 0) {
            float B[4];
#pragma unroll
            for (int blk = 0; blk < 4; ++blk) {
                const float* r = &accs[w][blk * 8];
                B[blk] = ((r[0] + r[1]) + (r[2] + r[3])) + ((r[4] + r[5]) + (r[6] + r[7]));
            }
            r2[t] = (B[0] + B[1]) + (B[2] + B[3]);
        }
    }

    // ---- loss partial ----
#pragma unroll
    for (int off = 32; off; off >>= 1) ls += __shfl_down(ls, off, 64);
    if (lane == 0) shl[w] = ls;
    __syncthreads();
    if (threadIdx.x == 0) partial[blockIdx.x] = (shl[0] + shl[1]) + (shl[2] + shl[3]);
}

__global__ __launch_bounds__(256) void k_finalize_loss(const float* __restrict__ partial,
                                                       float* __restrict__ loss_out)
{
    double s = 0.0;
    for (int i = threadIdx.x; i < NQ * (NTOK / 4); i += 256) s += (double)partial[i];
#pragma unroll
    for (int off = 32; off; off >>= 1) s += __shfl_down(s, off, 64);
    __shared__ double sh[4];
    if ((threadIdx.x & 63) == 0) sh[threadIdx.x >> 6] = s;
    __syncthreads();
    if (threadIdx.x == 0) {
        double tot = (sh[0] + sh[1]) + (sh[2] + sh[3]);
        loss_out[0] = (float)(tot * 1.25 / ((double)NQ * (double)QELEM));
    }
}

extern "C" void kernel_launch(void* const* d_in, const int* in_sizes, int n_in,
                              void* d_out, int out_size, void* d_ws, size_t ws_size,
                              hipStream_t stream)
{
    const float* x   = (const float*)d_in[0];
    const float* cbs = (const float*)d_in[1];

    float* qout     = (float*)d_out;
    float* idx_out  = qout + QELEM;
    float* loss_out = idx_out + (size_t)NTOK * NQ;
    float* R        = qout;                 // residual lives in d_out (validated R5)

    char* ws = (char*)d_ws;
    size_t off = 0;
    unsigned short* Rb   = (unsigned short*)(ws + off); off += (size_t)QELEM * 2;  // 16MB
    unsigned short* Cbb  = (unsigned short*)(ws + off); off += (size_t)QELEM * 2;  // 16MB
    float*          c2   = (float*)(ws + off);          off += (size_t)NQ * KCB * 4;
    float*          r2   = (float*)(ws + off);          off += (size_t)NTOK * 4;
    float*          part = (float*)(ws + off);          off += (size_t)NQ * (NTOK / 4) * 4;
    float*          candS= (float*)(ws + off);          off += (size_t)NTOK * 64 * 4; // 4MB
    int*            candI= (int*)(ws + off);            off += (size_t)NTOK * 64 * 4; // 4MB

    // fused init: x rows (R copy, Rb cast, r2) + cb rows (Cbb cast, c2)
    k_initnorm<<<NTOK / 4 + NQ * KCB / 4, 256, 0, stream>>>(
        x, cbs, (float4*)R, (ushort4*)Rb, (ushort4*)Cbb, r2, c2);

    for (int q = 0; q < NQ; ++q) {
        const float*          cbq  = cbs + (size_t)q * KCB * DIM;
        const unsigned short* cbbq = Cbb + (size_t)q * KCB * DIM;
        const float*          c2q  = c2 + (size_t)q * KCB;
        dim3 g(NBLK2, NTOK / 256);
        k_gemm_topk<<<g, 512, 0, stream>>>(Rb, cbbq, c2q, candS, candI);
        k_selupd<<<NTOK / 4, 256, 0, stream>>>(candS, candI, R, cbq, r2, c2q,
                                               idx_out, part + (size_t)q * (NTOK / 4),
                                               (ushort4*)Rb, (const float4*)x, q);
    }

    k_finalize_loss<<<1, 256, 0, stream>>>(part, loss_out);
}